// Round 7
// baseline (222.634 us; speedup 1.0000x reference)
//
#include <hip/hip_runtime.h>

// Problem constants (setup_inputs: B=256, T=16, H=W=160, sms=2 -> t=16, h=w=80)
#define T_DIM 16
#define H2 80
#define W2 80
#define SLICE (H2 * W2)          // 6400 floats per t-slice
#define SAMPLE (T_DIM * SLICE)   // 102400 floats per sample
#define BANDS 5                  // row-bands per sample
#define ROWS_PER_BAND (H2 / BANDS)  // 16 rows
#define BLOCK (ROWS_PER_BAND * W2 / 4)  // 320 threads, one float4 each per slice

__device__ __forceinline__ float4 relu4(float4 v) {
    v.x = fmaxf(v.x, 0.f); v.y = fmaxf(v.y, 0.f);
    v.z = fmaxf(v.z, 0.f); v.w = fmaxf(v.w, 0.f);
    return v;
}

// Phase 1: per-sample linear sums (S0, Sx, Sy, Sq) + TV sums (h, w, t).
// Round-0 geometry (fastest measured: 1280 blocks x 320 thr, row-major
// coalesced own-f4, register t-diff, no cross-lane ops) with ONE change:
// the h-neighbor row and w-boundary scalar come from a double-buffered LDS
// tile instead of redundant global reloads. This cuts L1 traffic per
// wave-iter from 2304B to ~1088B (own 1024 + 20-lane band-edge fallback),
// which the L1-throughput model (~10-12 B/cyc/CU, matches r0's ~33us at
// 236MB) says is the dominant cost. One barrier per t-iter; double buffer
// makes that sufficient: iter i's LDS reads are lgkm-drained before iter
// i+1's barrier, which all waves pass before iter i+2 overwrites buf[i&1].
__global__ __launch_bounds__(BLOCK) void tsr_phase1(const float* __restrict__ scores,
                                                    float* __restrict__ ws) {
    __shared__ float lbuf[2][ROWS_PER_BAND][W2];   // 2 x 5120 B
    __shared__ float red[(BLOCK / 64) * 7];

    const int blk  = blockIdx.x;
    const int b    = blk / BANDS;
    const int band = blk % BANDS;
    const int tid  = threadIdx.x;
    const int lane = tid & 63;

    const int r   = tid / (W2 / 4);   // local row 0..15
    const int cx  = tid % (W2 / 4);   // float4 index within row, 0..19
    const int y0  = band * ROWS_PER_BAND;
    const int y   = y0 + r;
    const int xb  = cx * 4;

    const float step = 2.0f / (float)(H2 - 1);   // h == w == 80 -> same step
    const float yy  = -1.0f + (float)y * step;
    const float xx0 = -1.0f + (float)(xb + 0) * step;
    const float xx1 = -1.0f + (float)(xb + 1) * step;
    const float xx2 = -1.0f + (float)(xb + 2) * step;
    const float xx3 = -1.0f + (float)(xb + 3) * step;
    const float yy2 = yy * yy;
    const float cq0 = xx0 * xx0 + yy2;
    const float cq1 = xx1 * xx1 + yy2;
    const float cq2 = xx2 * xx2 + yy2;
    const float cq3 = xx3 * xx3 + yy2;

    const float* sampBase = scores + (size_t)b * SAMPLE;
    const int rowOff = y * W2 + xb;                          // own float4 (floats)
    const bool hEdge = (r == ROWS_PER_BAND - 1);             // band-bottom row
    const int  hOff  = (y + 1 < H2) ? rowOff + W2 : rowOff;  // clamp -> diff 0 at y==79
    const bool wEnd  = (cx == (W2 / 4) - 1);                 // row end -> diff 0

    float s0 = 0.f, sx = 0.f, sy = 0.f, sq = 0.f;
    float tvh = 0.f, tvw = 0.f, tvt = 0.f;
    float4 prev = make_float4(0.f, 0.f, 0.f, 0.f);

    for (int t = 0; t < T_DIM; ++t) {
        const float* sl = sampBase + (size_t)t * SLICE;
        const float4 v = relu4(*(const float4*)(sl + rowOff));

        // stage own (relu'd) f4 into this iter's LDS buffer
        *(float4*)&lbuf[t & 1][r][xb] = v;

        // band-edge h-neighbor: global (next band's first row / clamped),
        // issued before the barrier so it overlaps the drain
        float4 hN;
        if (hEdge) hN = relu4(*(const float4*)(sl + hOff));   // 20 lanes (wave 4)

        __syncthreads();

        if (!hEdge) hN = *(const float4*)&lbuf[t & 1][r + 1][xb];
        const float wN = wEnd ? v.w : lbuf[t & 1][r][xb + 4];

        // linear sums
        const float rs = (v.x + v.y) + (v.z + v.w);
        s0 += rs;
        sy = fmaf(yy, rs, sy);
        sx = fmaf(xx0, v.x, sx); sx = fmaf(xx1, v.y, sx);
        sx = fmaf(xx2, v.z, sx); sx = fmaf(xx3, v.w, sx);
        sq = fmaf(cq0, v.x, sq); sq = fmaf(cq1, v.y, sq);
        sq = fmaf(cq2, v.z, sq); sq = fmaf(cq3, v.w, sq);

        // w-diffs: 3 internal + boundary (0 at row end)
        tvw += fabsf(v.y - v.x) + fabsf(v.z - v.y) + fabsf(v.w - v.z)
             + fabsf(wN - v.w);

        // h-diffs vs next row (clamped -> 0 at y==79)
        tvh += fabsf(hN.x - v.x) + fabsf(hN.y - v.y) +
               fabsf(hN.z - v.z) + fabsf(hN.w - v.w);

        // t-diffs: register-resident
        if (t > 0) {
            tvt += fabsf(v.x - prev.x) + fabsf(v.y - prev.y) +
                   fabsf(v.z - prev.z) + fabsf(v.w - prev.w);
        }
        prev = v;
    }

    // block reduction: wave shuffle, then cross-wave via LDS
    float acc[7] = {s0, sx, sy, sq, tvh, tvw, tvt};
#pragma unroll
    for (int off = 32; off > 0; off >>= 1) {
#pragma unroll
        for (int i = 0; i < 7; ++i) acc[i] += __shfl_down(acc[i], off);
    }
    const int wave = tid >> 6;
    if (lane == 0) {
#pragma unroll
        for (int i = 0; i < 7; ++i) red[wave * 7 + i] = acc[i];
    }
    __syncthreads();
    if (tid < 7) {
        float s = 0.f;
#pragma unroll
        for (int wv = 0; wv < BLOCK / 64; ++wv) s += red[wv * 7 + tid];
        ws[blk * 8 + tid] = s;  // distinct slot per block -> no init, no atomics
    }
}

// Phase 2: sum band partials per sample, nonlinear combine, batch mean -> scalar
__global__ __launch_bounds__(256) void tsr_finalize(const float* __restrict__ ws,
                                                    float* __restrict__ out, int B) {
    __shared__ float red[256];
    const int tid = threadIdx.x;
    float acc = 0.f;
    const float ch = 1.0f / (float)(T_DIM * (H2 - 1) * W2);       // 1/101120
    const float cw = 1.0f / (float)(T_DIM * H2 * (W2 - 1));       // 1/101120
    const float ct = 0.3f / (float)((T_DIM - 1) * H2 * W2);       // 0.3/96000
    for (int b = tid; b < B; b += 256) {
        float p[7] = {0.f, 0.f, 0.f, 0.f, 0.f, 0.f, 0.f};
        for (int band = 0; band < BANDS; ++band) {
            const float* w = ws + (size_t)(b * BANDS + band) * 8;
#pragma unroll
            for (int i = 0; i < 7; ++i) p[i] += w[i];
        }
        const float S0 = p[0], Sx = p[1], Sy = p[2], Sq = p[3];
        const float Th = p[4], Tw = p[5], Tt = p[6];
        const float tot = fmaxf(S0, 1e-6f);
        const float inv = 1.0f / tot;
        const float mux = Sx * inv, muy = Sy * inv;
        const float m2 = mux * mux + muy * muy;
        const float compact = Sq * inv - 2.0f * m2 + m2 * (S0 * inv);
        const float tv = Th * ch + Tw * cw + Tt * ct;
        acc += compact + tv;
    }
    red[tid] = acc;
    __syncthreads();
    for (int s = 128; s > 0; s >>= 1) {
        if (tid < s) red[tid] += red[tid + s];
        __syncthreads();
    }
    if (tid == 0) out[0] = red[0] / (float)B;
}

extern "C" void kernel_launch(void* const* d_in, const int* in_sizes, int n_in,
                              void* d_out, int out_size, void* d_ws, size_t ws_size,
                              hipStream_t stream) {
    const float* scores = (const float*)d_in[0];
    const int B = in_sizes[0] / SAMPLE;  // 256
    float* ws = (float*)d_ws;

    tsr_phase1<<<B * BANDS, BLOCK, 0, stream>>>(scores, ws);
    tsr_finalize<<<1, 256, 0, stream>>>(ws, (float*)d_out, B);
}

// Round 8
// 157.314 us; speedup vs baseline: 1.4152x; 1.4152x over previous
//
#include <hip/hip_runtime.h>

// Problem constants (setup_inputs: B=256, T=16, H=W=160, sms=2 -> t=16, h=w=80)
#define T_DIM 16
#define H2 80
#define W2 80
#define SLICE (H2 * W2)          // 6400 floats per t-slice
#define SAMPLE (T_DIM * SLICE)   // 102400 floats per sample
#define PARTS 3                  // bands per sample: rows 0-31, 32-63 (2-row strips), 64-79 (single)
#define BLOCK 320                // 5 waves

__device__ __forceinline__ float4 relu4(float4 v) {
    v.x = fmaxf(v.x, 0.f); v.y = fmaxf(v.y, 0.f);
    v.z = fmaxf(v.z, 0.f); v.w = fmaxf(v.w, 0.f);
    return v;
}

// Phase 1: per-sample linear sums (S0, Sx, Sy, Sq) + TV sums (h, w, t).
// Surviving model (r0..r7): time ~ bytes through the per-CU vector-memory
// path (~11.6 B/cyc/CU), given coalesced own-loads, NO cross-lane ops in the
// dep chain (r1/r3 regressions), NO hot-loop barriers (r7 regression), and
// moderate VGPR with enough resident waves (r4 regression). This version cuts
// bytes 18% vs the r0 structure by 2-ROW REGISTER STRIPS on 64 of 80 rows:
//   bands 0,1 (rows 0-31, 32-63): thread owns rows (2s, 2s+1) at one f4-col.
//     h-diff (2s,2s+1) is register-local; only row 2s+2 is loaded (L1 hit).
//     56B/thread-iter for 32B own (1.75x) vs r0's 36B/16B (2.25x).
//   band 2 (rows 64-79): exact r0 single-row path (ragged tail, same block).
// h-pair coverage: band0 internal (0,1)..(30,31) + hN (1,2)..(31,32);
// band1 internal (32,33)..(62,63) + hN (33,34)..(63,64); band2 (64,65)..
// (78,79) + clamp(79)=0. Every pair 0..78 exactly once. No seed reloads,
// register t-diffs, no barriers, no shuffles.
__global__ __launch_bounds__(BLOCK) void tsr_phase1(const float* __restrict__ scores,
                                                    float* __restrict__ ws) {
    __shared__ float red[(BLOCK / 64) * 7];

    const int blk  = blockIdx.x;
    const int b    = blk / PARTS;
    const int band = blk % PARTS;
    const int tid  = threadIdx.x;
    const int lane = tid & 63;

    const float step = 2.0f / (float)(H2 - 1);   // h == w == 80 -> same step
    const float* sampBase = scores + (size_t)b * SAMPLE;

    float s0 = 0.f, sx = 0.f, sy = 0.f, sq = 0.f;
    float tvh = 0.f, tvw = 0.f, tvt = 0.f;

    const int cx = tid % 20;          // f4 column 0..19 (both modes)
    const int xb = cx * 4;
    const float xx0 = -1.0f + (float)xb * step;
    const float xx1 = xx0 + step, xx2 = xx1 + step, xx3 = xx2 + step;
    const float xs0 = xx0 * xx0, xs1 = xx1 * xx1;
    const float xs2 = xx2 * xx2, xs3 = xx3 * xx3;

    if (band < 2) {
        // ---- 2-row strip mode: rows y0 = band*32 + 2*strip, y0+1 ----
        const int strip = tid / 20;               // 0..15
        const int y0 = band * 32 + strip * 2;     // even row; max 62
        const int off0 = y0 * W2 + xb;            // own row A
        const int off1 = off0 + W2;               // own row B
        const int offH = off1 + W2;               // neighbor row (<=64, always valid)
        const int w0   = (cx < 19) ? off0 + 4 : off0 + 3;  // clamp -> diff 0
        const int w1   = w0 + W2;

        const float yyA = -1.0f + (float)y0 * step;
        const float yyB = yyA + step;
        const float ysA = yyA * yyA, ysB = yyB * yyB;

        float4 prev0 = make_float4(0.f, 0.f, 0.f, 0.f);
        float4 prev1 = prev0;

#pragma unroll 4
        for (int t = 0; t < T_DIM; ++t) {
            const float* sl = sampBase + (size_t)t * SLICE;
            // 5 independent loads (one base, imm-folded offsets), then compute
            const float4 v0 = relu4(*(const float4*)(sl + off0));
            const float4 v1 = relu4(*(const float4*)(sl + off1));
            const float4 hN = relu4(*(const float4*)(sl + offH));
            const float wn0 = fmaxf(sl[w0], 0.f);
            const float wn1 = fmaxf(sl[w1], 0.f);

            // column sums fold the x-moments for both rows at once
            const float c0 = v0.x + v1.x, c1 = v0.y + v1.y;
            const float c2 = v0.z + v1.z, c3 = v0.w + v1.w;
            const float rs0 = (v0.x + v0.y) + (v0.z + v0.w);
            const float rs1 = (v1.x + v1.y) + (v1.z + v1.w);
            s0 += (c0 + c1) + (c2 + c3);
            sx = fmaf(xx0, c0, sx); sx = fmaf(xx1, c1, sx);
            sx = fmaf(xx2, c2, sx); sx = fmaf(xx3, c3, sx);
            sy = fmaf(yyA, rs0, sy); sy = fmaf(yyB, rs1, sy);
            sq = fmaf(xs0, c0, sq); sq = fmaf(xs1, c1, sq);
            sq = fmaf(xs2, c2, sq); sq = fmaf(xs3, c3, sq);
            sq = fmaf(ysA, rs0, sq); sq = fmaf(ysB, rs1, sq);

            // w-diffs: 3 internal + boundary per row (boundary 0 at cx==19)
            tvw += fabsf(v0.y - v0.x) + fabsf(v0.z - v0.y) + fabsf(v0.w - v0.z)
                 + fabsf(wn0 - v0.w)
                 + fabsf(v1.y - v1.x) + fabsf(v1.z - v1.y) + fabsf(v1.w - v1.z)
                 + fabsf(wn1 - v1.w);

            // h-diffs: register-local pair + loaded neighbor
            tvh += fabsf(v1.x - v0.x) + fabsf(v1.y - v0.y) +
                   fabsf(v1.z - v0.z) + fabsf(v1.w - v0.w)
                 + fabsf(hN.x - v1.x) + fabsf(hN.y - v1.y) +
                   fabsf(hN.z - v1.z) + fabsf(hN.w - v1.w);

            // t-diffs: register-resident, both rows
            if (t > 0) {
                tvt += fabsf(v0.x - prev0.x) + fabsf(v0.y - prev0.y) +
                       fabsf(v0.z - prev0.z) + fabsf(v0.w - prev0.w)
                     + fabsf(v1.x - prev1.x) + fabsf(v1.y - prev1.y) +
                       fabsf(v1.z - prev1.z) + fabsf(v1.w - prev1.w);
            }
            prev0 = v0; prev1 = v1;
        }
    } else {
        // ---- r0 single-row mode: rows 64..79 ----
        const int r = tid / 20;                   // 0..15
        const int y = 64 + r;
        const int rowOff = y * W2 + xb;
        const int hOff = (y + 1 < H2) ? rowOff + W2 : rowOff;  // clamp -> diff 0
        const int wOff = (cx < 19) ? rowOff + 4 : rowOff + 3;  // clamp -> diff 0

        const float yy = -1.0f + (float)y * step;
        const float yy2 = yy * yy;
        const float cq0 = xs0 + yy2, cq1 = xs1 + yy2;
        const float cq2 = xs2 + yy2, cq3 = xs3 + yy2;

        float4 prev = make_float4(0.f, 0.f, 0.f, 0.f);

#pragma unroll 4
        for (int t = 0; t < T_DIM; ++t) {
            const float* sl = sampBase + (size_t)t * SLICE;
            const float4 v  = relu4(*(const float4*)(sl + rowOff));
            const float4 hN = relu4(*(const float4*)(sl + hOff));
            const float  wN = fmaxf(sl[wOff], 0.f);

            const float rs = (v.x + v.y) + (v.z + v.w);
            s0 += rs;
            sy = fmaf(yy, rs, sy);
            sx = fmaf(xx0, v.x, sx); sx = fmaf(xx1, v.y, sx);
            sx = fmaf(xx2, v.z, sx); sx = fmaf(xx3, v.w, sx);
            sq = fmaf(cq0, v.x, sq); sq = fmaf(cq1, v.y, sq);
            sq = fmaf(cq2, v.z, sq); sq = fmaf(cq3, v.w, sq);

            tvw += fabsf(v.y - v.x) + fabsf(v.z - v.y) + fabsf(v.w - v.z)
                 + fabsf(wN - v.w);
            tvh += fabsf(hN.x - v.x) + fabsf(hN.y - v.y) +
                   fabsf(hN.z - v.z) + fabsf(hN.w - v.w);
            if (t > 0) {
                tvt += fabsf(v.x - prev.x) + fabsf(v.y - prev.y) +
                       fabsf(v.z - prev.z) + fabsf(v.w - prev.w);
            }
            prev = v;
        }
    }

    // block reduction: wave shuffle, then cross-wave via LDS
    float acc[7] = {s0, sx, sy, sq, tvh, tvw, tvt};
#pragma unroll
    for (int off = 32; off > 0; off >>= 1) {
#pragma unroll
        for (int i = 0; i < 7; ++i) acc[i] += __shfl_down(acc[i], off);
    }
    const int wave = tid >> 6;
    if (lane == 0) {
#pragma unroll
        for (int i = 0; i < 7; ++i) red[wave * 7 + i] = acc[i];
    }
    __syncthreads();
    if (tid < 7) {
        float s = 0.f;
#pragma unroll
        for (int wv = 0; wv < BLOCK / 64; ++wv) s += red[wv * 7 + tid];
        ws[blk * 8 + tid] = s;  // distinct slot per block -> no init, no atomics
    }
}

// Phase 2: sum the 3 band partials per sample, nonlinear combine, batch mean
__global__ __launch_bounds__(256) void tsr_finalize(const float* __restrict__ ws,
                                                    float* __restrict__ out, int B) {
    __shared__ float red[256];
    const int tid = threadIdx.x;
    float acc = 0.f;
    const float ch = 1.0f / (float)(T_DIM * (H2 - 1) * W2);       // 1/101120
    const float cw = 1.0f / (float)(T_DIM * H2 * (W2 - 1));       // 1/101120
    const float ct = 0.3f / (float)((T_DIM - 1) * H2 * W2);       // 0.3/96000
    for (int b = tid; b < B; b += 256) {
        float p[7] = {0.f, 0.f, 0.f, 0.f, 0.f, 0.f, 0.f};
        for (int part = 0; part < PARTS; ++part) {
            const float* w = ws + (size_t)(b * PARTS + part) * 8;
#pragma unroll
            for (int i = 0; i < 7; ++i) p[i] += w[i];
        }
        const float S0 = p[0], Sx = p[1], Sy = p[2], Sq = p[3];
        const float Th = p[4], Tw = p[5], Tt = p[6];
        const float tot = fmaxf(S0, 1e-6f);
        const float inv = 1.0f / tot;
        const float mux = Sx * inv, muy = Sy * inv;
        const float m2 = mux * mux + muy * muy;
        const float compact = Sq * inv - 2.0f * m2 + m2 * (S0 * inv);
        const float tv = Th * ch + Tw * cw + Tt * ct;
        acc += compact + tv;
    }
    red[tid] = acc;
    __syncthreads();
    for (int s = 128; s > 0; s >>= 1) {
        if (tid < s) red[tid] += red[tid + s];
        __syncthreads();
    }
    if (tid == 0) out[0] = red[0] / (float)B;
}

extern "C" void kernel_launch(void* const* d_in, const int* in_sizes, int n_in,
                              void* d_out, int out_size, void* d_ws, size_t ws_size,
                              hipStream_t stream) {
    const float* scores = (const float*)d_in[0];
    const int B = in_sizes[0] / SAMPLE;  // 256
    float* ws = (float*)d_ws;

    tsr_phase1<<<B * PARTS, BLOCK, 0, stream>>>(scores, ws);
    tsr_finalize<<<1, 256, 0, stream>>>(ws, (float*)d_out, B);
}